// Round 10
// baseline (200.481 us; speedup 1.0000x reference)
//
#include <hip/hip_runtime.h>
#include <cstddef>

#define EMBED 512
#define NHEADS 8
#define HD 64
#define SEQ 2048
#define NBH 16      // B * NHEADS
#define MROWS 4096  // B * SEQ

typedef __attribute__((ext_vector_type(8))) short bf16x8;
typedef __attribute__((ext_vector_type(4))) float f32x4;

__device__ __forceinline__ unsigned short f2bf(float x) {
    union { float f; unsigned u; } v; v.f = x;
    unsigned r = v.u + 0x7fffu + ((v.u >> 16) & 1u);
    return (unsigned short)(r >> 16);
}
__device__ __forceinline__ float bf2f(unsigned short u) {
    union { unsigned u; float f; } v; v.u = ((unsigned)u) << 16;
    return v.f;
}

// ---------------------------------------------------------------------------
// K0a: split x (fp32) into x_hi + x_lo (bf16 each).
// ---------------------------------------------------------------------------
__global__ __launch_bounds__(256) void cvt_x(
    const float* __restrict__ x, unsigned short* __restrict__ xh,
    unsigned short* __restrict__ xl)
{
    const int i = blockIdx.x * 256 + threadIdx.x;      // float4 index
    float4 v = ((const float4*)x)[i];
    ushort4 h, lo;
    h.x = f2bf(v.x); lo.x = f2bf(v.x - bf2f(h.x));
    h.y = f2bf(v.y); lo.y = f2bf(v.y - bf2f(h.y));
    h.z = f2bf(v.z); lo.z = f2bf(v.z - bf2f(h.z));
    h.w = f2bf(v.w); lo.w = f2bf(v.w - bf2f(h.w));
    ((ushort4*)xh)[i] = h;
    ((ushort4*)xl)[i] = lo;
}

// ---------------------------------------------------------------------------
// K0b: weight transposes to bf16.  z=0..2: Wq/Wk/Wv -> wt[z][n][k] (hi only).
// z=3: Wo hi -> wto[0];  z=4: Wo lo -> wto[1].
// ---------------------------------------------------------------------------
__global__ __launch_bounds__(256) void cvt_w(
    const float* __restrict__ Wq, const float* __restrict__ Wk,
    const float* __restrict__ Wv, const float* __restrict__ Wo,
    unsigned short* __restrict__ wt, unsigned short* __restrict__ wto)
{
    __shared__ float Ws[64][65];
    const int z = blockIdx.z;
    const float* __restrict__ W = (z == 0) ? Wq : (z == 1) ? Wk : (z == 2) ? Wv : Wo;
    const int k0 = blockIdx.x * 64, n0 = blockIdx.y * 64;
    const int t = threadIdx.x;
#pragma unroll
    for (int l = 0; l < 4; ++l) {
        const int idx = t + 256 * l;
        const int r = idx >> 4, c4 = (idx & 15) * 4;
        float4 w = *(const float4*)(W + (size_t)(k0 + r) * EMBED + n0 + c4);
        Ws[r][c4 + 0] = w.x; Ws[r][c4 + 1] = w.y;
        Ws[r][c4 + 2] = w.z; Ws[r][c4 + 3] = w.w;
    }
    __syncthreads();
    unsigned short* __restrict__ dst =
        (z < 3) ? (wt + (size_t)z * EMBED * EMBED)
                : (wto + (size_t)(z - 3) * EMBED * EMBED);
#pragma unroll
    for (int l = 0; l < 4; ++l) {
        const int idx = t + 256 * l;
        const int rn = idx >> 4, k4 = (idx & 15) * 4;
        ushort4 o;
        if (z == 4) {
            float v0 = Ws[k4 + 0][rn], v1 = Ws[k4 + 1][rn];
            float v2 = Ws[k4 + 2][rn], v3 = Ws[k4 + 3][rn];
            o.x = f2bf(v0 - bf2f(f2bf(v0)));
            o.y = f2bf(v1 - bf2f(f2bf(v1)));
            o.z = f2bf(v2 - bf2f(f2bf(v2)));
            o.w = f2bf(v3 - bf2f(f2bf(v3)));
        } else {
            o.x = f2bf(Ws[k4 + 0][rn]);
            o.y = f2bf(Ws[k4 + 1][rn]);
            o.z = f2bf(Ws[k4 + 2][rn]);
            o.w = f2bf(Ws[k4 + 3][rn]);
        }
        *(ushort4*)(dst + (size_t)(n0 + rn) * EMBED + k0 + k4) = o;
    }
}

// ---------------------------------------------------------------------------
// K1: QKV projection on MFMA.  out = (x_hi + x_lo) @ W_z + b_z, bf16 out.
// v written to vt with per-32 kv permutation (so PV B-frags are 16B).
// ---------------------------------------------------------------------------
__global__ __launch_bounds__(256) void mha_qkv_mfma(
    const unsigned short* __restrict__ xh, const unsigned short* __restrict__ xl,
    const unsigned short* __restrict__ wt,
    const float* __restrict__ bq, const float* __restrict__ bk,
    const float* __restrict__ bv,
    unsigned short* __restrict__ qo, unsigned short* __restrict__ ko,
    unsigned short* __restrict__ vt)
{
    const int m0 = blockIdx.x * 64;
    const int z  = blockIdx.y >> 3;
    const int n0 = (blockIdx.y & 7) * 64;
    const float* __restrict__ bias = (z == 0) ? bq : (z == 1) ? bk : bv;

    const int t = threadIdx.x;
    const int w = t >> 6;
    const int lane = t & 63;
    const int g = lane >> 4;
    const int c = lane & 15;

    const short* ah_row = (const short*)xh + (size_t)(m0 + 16 * w + c) * EMBED + 8 * g;
    const short* al_row = (const short*)xl + (size_t)(m0 + 16 * w + c) * EMBED + 8 * g;
    const short* wz = (const short*)wt + (size_t)z * EMBED * EMBED + 8 * g;

    f32x4 acc[4];
#pragma unroll
    for (int s = 0; s < 4; ++s) acc[s] = (f32x4){0.f, 0.f, 0.f, 0.f};

#pragma unroll 4
    for (int ch = 0; ch < 16; ++ch) {
        const int k0 = ch * 32;
        const bf16x8 ah = *(const bf16x8*)(ah_row + k0);
        const bf16x8 al = *(const bf16x8*)(al_row + k0);
#pragma unroll
        for (int s = 0; s < 4; ++s) {
            const bf16x8 bs = *(const bf16x8*)(wz + (size_t)(n0 + 16 * s + c) * EMBED + k0);
            acc[s] = __builtin_amdgcn_mfma_f32_16x16x32_bf16(ah, bs, acc[s], 0, 0, 0);
            acc[s] = __builtin_amdgcn_mfma_f32_16x16x32_bf16(al, bs, acc[s], 0, 0, 0);
        }
    }

    if (z < 2) {
        unsigned short* __restrict__ out = (z == 0) ? qo : ko;
#pragma unroll
        for (int s = 0; s < 4; ++s) {
            const int n = n0 + 16 * s + c;
            const int h = n >> 6, d = n & 63;
            const float bb = bias[n];
#pragma unroll
            for (int r = 0; r < 4; ++r) {
                const int m  = m0 + 16 * w + 4 * g + r;
                const int b_ = m >> 11, sm = m & 2047;
                out[((size_t)(b_ * NHEADS + h) * SEQ + sm) * HD + d] =
                    f2bf(acc[s][r] + bb);
            }
        }
    } else {
        const int m  = m0 + 16 * w + 4 * g;     // base kv of the 4-row chunk
        const int b_ = m >> 11, sm = m & 2047;
        const int a  = sm >> 5, rem = sm & 31;
        const int pos = 32 * a + 8 * ((rem & 15) >> 2) + ((rem >> 4) << 2);
        const int h  = n0 >> 6;
#pragma unroll
        for (int s = 0; s < 4; ++s) {
            const int d = 16 * s + c;
            const float bb = bias[n0 + d];
            ushort4 o;
            o.x = f2bf(acc[s][0] + bb);
            o.y = f2bf(acc[s][1] + bb);
            o.z = f2bf(acc[s][2] + bb);
            o.w = f2bf(acc[s][3] + bb);
            *(ushort4*)(vt + ((size_t)(b_ * NHEADS + h) * HD + d) * SEQ + pos) = o;
        }
    }
}

// ---------------------------------------------------------------------------
// K2: fused flash attention, LDS-staged K/V (XOR-swizzled), 2-DEEP pipelined
// (4 LDS tile slots, kt unrolled x2, one barrier per 2 kt).
// Pass 1: row sums of exp2(s*scale2).  Pass 2: normalized weights + PV.
// O written as uint32 (bf16 hi<<16 | bf16 lo) per element.
// ---------------------------------------------------------------------------
__global__ __launch_bounds__(256) void mha_fused(
    const short* __restrict__ qb, const short* __restrict__ kb,
    const short* __restrict__ vt,
    float* __restrict__ wts, unsigned* __restrict__ attn)
{
    __shared__ short Ks[4][64 * 64];
    __shared__ short Vs[4][64 * 64];

    const int bh = blockIdx.y;
    const int q0 = blockIdx.x * 64;
    const int t = threadIdx.x;
    const int w = t >> 6;
    const int lane = t & 63;
    const int g = lane >> 4;
    const int c = lane & 15;
    const int q = q0 + w * 16 + c;

    const short* qrow = qb + ((size_t)bh * SEQ + q) * HD + 8 * g;
    const bf16x8 qf0 = *(const bf16x8*)(qrow);
    const bf16x8 qf1 = *(const bf16x8*)(qrow + 32);

    const int r0 = t >> 3, bl0 = t & 7;
    const int r1 = r0 + 32;
    const int ds0 = r0 * 64 + (((bl0) ^ (r0 & 7)) << 3);
    const int ds1 = r1 * 64 + (((bl0) ^ (r1 & 7)) << 3);
    const short* kgb = kb + (size_t)bh * SEQ * HD;
    const short* vgb = vt + (size_t)bh * HD * SEQ;

    int koff[4][2];
#pragma unroll
    for (int s = 0; s < 4; ++s) {
        const int rr = c + 16 * s;
        koff[s][0] = rr * 64 + (((g    ) ^ (rr & 7)) << 3);
        koff[s][1] = rr * 64 + (((g + 4) ^ (rr & 7)) << 3);
    }
    int voff2[4][2];
#pragma unroll
    for (int s = 0; s < 4; ++s) {
        const int rv = 16 * s + c;
        voff2[s][0] = rv * 64 + (((g    ) ^ (rv & 7)) << 3);
        voff2[s][1] = rv * 64 + (((g + 4) ^ (rv & 7)) << 3);
    }

    const float scale2 = 0.125f * 1.44269504f;   // 1/sqrt(64) * log2(e)

    // ---- pass 1: row sums of exp2(s*scale2), K staged 2-deep ------------
    float l = 0.f;

    auto sum_tile = [&](const short* Kb) {
        f32x4 a0 = {0.f,0.f,0.f,0.f}, a1 = {0.f,0.f,0.f,0.f};
        f32x4 a2 = {0.f,0.f,0.f,0.f}, a3 = {0.f,0.f,0.f,0.f};
        __builtin_amdgcn_s_setprio(1);
        a0 = __builtin_amdgcn_mfma_f32_16x16x32_bf16(*(const bf16x8*)(Kb + koff[0][0]), qf0, a0, 0, 0, 0);
        a0 = __builtin_amdgcn_mfma_f32_16x16x32_bf16(*(const bf16x8*)(Kb + koff[0][1]), qf1, a0, 0, 0, 0);
        a1 = __builtin_amdgcn_mfma_f32_16x16x32_bf16(*(const bf16x8*)(Kb + koff[1][0]), qf0, a1, 0, 0, 0);
        a1 = __builtin_amdgcn_mfma_f32_16x16x32_bf16(*(const bf16x8*)(Kb + koff[1][1]), qf1, a1, 0, 0, 0);
        a2 = __builtin_amdgcn_mfma_f32_16x16x32_bf16(*(const bf16x8*)(Kb + koff[2][0]), qf0, a2, 0, 0, 0);
        a2 = __builtin_amdgcn_mfma_f32_16x16x32_bf16(*(const bf16x8*)(Kb + koff[2][1]), qf1, a2, 0, 0, 0);
        a3 = __builtin_amdgcn_mfma_f32_16x16x32_bf16(*(const bf16x8*)(Kb + koff[3][0]), qf0, a3, 0, 0, 0);
        a3 = __builtin_amdgcn_mfma_f32_16x16x32_bf16(*(const bf16x8*)(Kb + koff[3][1]), qf1, a3, 0, 0, 0);
        __builtin_amdgcn_s_setprio(0);
        float ts = 0.f;
#pragma unroll
        for (int r = 0; r < 4; ++r) {
            ts += __builtin_amdgcn_exp2f(a0[r] * scale2);
            ts += __builtin_amdgcn_exp2f(a1[r] * scale2);
            ts += __builtin_amdgcn_exp2f(a2[r] * scale2);
            ts += __builtin_amdgcn_exp2f(a3[r] * scale2);
        }
        ts += __shfl_xor(ts, 16);
        ts += __shfl_xor(ts, 32);
        l += ts;
    };

    {   // prologue: stage tiles 0,1
        uint4 kaA = *(const uint4*)(kgb + (size_t)t * 8);
        uint4 kcA = *(const uint4*)(kgb + (size_t)(t + 256) * 8);
        const short* kg1 = kgb + (size_t)64 * HD;
        uint4 kaB = *(const uint4*)(kg1 + (size_t)t * 8);
        uint4 kcB = *(const uint4*)(kg1 + (size_t)(t + 256) * 8);
        *(uint4*)(&Ks[0][ds0]) = kaA;  *(uint4*)(&Ks[0][ds1]) = kcA;
        *(uint4*)(&Ks[1][ds0]) = kaB;  *(uint4*)(&Ks[1][ds1]) = kcB;
    }
    __syncthreads();
    for (int kt = 0; kt < 32; kt += 2) {
        uint4 kaA, kcA, kaB, kcB;
        if (kt < 30) {
            const short* kgA = kgb + (size_t)(kt + 2) * 64 * HD;
            const short* kgB = kgb + (size_t)(kt + 3) * 64 * HD;
            kaA = *(const uint4*)(kgA + (size_t)t * 8);
            kcA = *(const uint4*)(kgA + (size_t)(t + 256) * 8);
            kaB = *(const uint4*)(kgB + (size_t)t * 8);
            kcB = *(const uint4*)(kgB + (size_t)(t + 256) * 8);
        }
        sum_tile(&Ks[kt & 3][0]);
        sum_tile(&Ks[(kt + 1) & 3][0]);
        if (kt < 30) {
            *(uint4*)(&Ks[(kt + 2) & 3][ds0]) = kaA;
            *(uint4*)(&Ks[(kt + 2) & 3][ds1]) = kcA;
            *(uint4*)(&Ks[(kt + 3) & 3][ds0]) = kaB;
            *(uint4*)(&Ks[(kt + 3) & 3][ds1]) = kcB;
        }
        __syncthreads();
    }

    const float c0 = -__builtin_amdgcn_logf(l);   // p = exp2(s*scale2 + c0)

    // ---- pass 2: weights + PV, K/V staged 2-deep ------------------------
    f32x4 o0 = {0.f,0.f,0.f,0.f}, o1 = {0.f,0.f,0.f,0.f};
    f32x4 o2 = {0.f,0.f,0.f,0.f}, o3 = {0.f,0.f,0.f,0.f};
    float* __restrict__ wrow = wts + ((size_t)bh * SEQ + q) * SEQ;

    auto pv_tile = [&](const short* Kb, const short* Vb, int kv0) {
        f32x4 a0 = {0.f,0.f,0.f,0.f}, a1 = {0.f,0.f,0.f,0.f};
        f32x4 a2 = {0.f,0.f,0.f,0.f}, a3 = {0.f,0.f,0.f,0.f};
        __builtin_amdgcn_s_setprio(1);
        a0 = __builtin_amdgcn_mfma_f32_16x16x32_bf16(*(const bf16x8*)(Kb + koff[0][0]), qf0, a0, 0, 0, 0);
        a0 = __builtin_amdgcn_mfma_f32_16x16x32_bf16(*(const bf16x8*)(Kb + koff[0][1]), qf1, a0, 0, 0, 0);
        a1 = __builtin_amdgcn_mfma_f32_16x16x32_bf16(*(const bf16x8*)(Kb + koff[1][0]), qf0, a1, 0, 0, 0);
        a1 = __builtin_amdgcn_mfma_f32_16x16x32_bf16(*(const bf16x8*)(Kb + koff[1][1]), qf1, a1, 0, 0, 0);
        a2 = __builtin_amdgcn_mfma_f32_16x16x32_bf16(*(const bf16x8*)(Kb + koff[2][0]), qf0, a2, 0, 0, 0);
        a2 = __builtin_amdgcn_mfma_f32_16x16x32_bf16(*(const bf16x8*)(Kb + koff[2][1]), qf1, a2, 0, 0, 0);
        a3 = __builtin_amdgcn_mfma_f32_16x16x32_bf16(*(const bf16x8*)(Kb + koff[3][0]), qf0, a3, 0, 0, 0);
        a3 = __builtin_amdgcn_mfma_f32_16x16x32_bf16(*(const bf16x8*)(Kb + koff[3][1]), qf1, a3, 0, 0, 0);
        __builtin_amdgcn_s_setprio(0);

        float pn[4][4];
#pragma unroll
        for (int r = 0; r < 4; ++r) {
            pn[0][r] = __builtin_amdgcn_exp2f(fmaf(a0[r], scale2, c0));
            pn[1][r] = __builtin_amdgcn_exp2f(fmaf(a1[r], scale2, c0));
            pn[2][r] = __builtin_amdgcn_exp2f(fmaf(a2[r], scale2, c0));
            pn[3][r] = __builtin_amdgcn_exp2f(fmaf(a3[r], scale2, c0));
        }
        bf16x8 pf0, pf1;
#pragma unroll
        for (int r = 0; r < 4; ++r) {
            pf0[r]     = (short)f2bf(pn[0][r]);
            pf0[r + 4] = (short)f2bf(pn[1][r]);
            pf1[r]     = (short)f2bf(pn[2][r]);
            pf1[r + 4] = (short)f2bf(pn[3][r]);
        }
        __builtin_amdgcn_s_setprio(1);
#pragma unroll
        for (int sub = 0; sub < 4; ++sub) {
            const bf16x8 vf0 = *(const bf16x8*)(Vb + voff2[sub][0]);
            const bf16x8 vf1 = *(const bf16x8*)(Vb + voff2[sub][1]);
            f32x4& o = (sub == 0) ? o0 : (sub == 1) ? o1 : (sub == 2) ? o2 : o3;
            o = __builtin_amdgcn_mfma_f32_16x16x32_bf16(pf0, vf0, o, 0, 0, 0);
            o = __builtin_amdgcn_mfma_f32_16x16x32_bf16(pf1, vf1, o, 0, 0, 0);
        }
        __builtin_amdgcn_s_setprio(0);
        // weights stores issued after PV so the matrix pipe is already busy
#pragma unroll
        for (int s = 0; s < 4; ++s) {
            float4 st;
            st.x = pn[s][0]; st.y = pn[s][1]; st.z = pn[s][2]; st.w = pn[s][3];
            *(float4*)(wrow + kv0 + 16 * s + 4 * g) = st;
        }
    };

    {   // prologue: stage tiles 0,1 (K and V)
        uint4 kaA = *(const uint4*)(kgb + (size_t)t * 8);
        uint4 kcA = *(const uint4*)(kgb + (size_t)(t + 256) * 8);
        uint4 vaA = *(const uint4*)(vgb + (size_t)r0 * SEQ + bl0 * 8);
        uint4 vbA = *(const uint4*)(vgb + (size_t)r1 * SEQ + bl0 * 8);
        const short* kg1 = kgb + (size_t)64 * HD;
        const short* vg1 = vgb + 64;
        uint4 kaB = *(const uint4*)(kg1 + (size_t)t * 8);
        uint4 kcB = *(const uint4*)(kg1 + (size_t)(t + 256) * 8);
        uint4 vaB = *(const uint4*)(vg1 + (size_t)r0 * SEQ + bl0 * 8);
        uint4 vbB = *(const uint4*)(vg1 + (size_t)r1 * SEQ + bl0 * 8);
        *(uint4*)(&Ks[0][ds0]) = kaA;  *(uint4*)(&Ks[0][ds1]) = kcA;
        *(uint4*)(&Vs[0][ds0]) = vaA;  *(uint4*)(&Vs[0][ds1]) = vbA;
        *(uint4*)(&Ks[1][ds0]) = kaB;  *(uint4*)(&Ks[1][ds1]) = kcB;
        *(uint4*)(&Vs[1][ds0]) = vaB;  *(uint4*)(&Vs[1][ds1]) = vbB;
    }
    __syncthreads();
    for (int kt = 0; kt < 32; kt += 2) {
        uint4 kaA, kcA, vaA, vbA, kaB, kcB, vaB, vbB;
        if (kt < 30) {
            const short* kgA = kgb + (size_t)(kt + 2) * 64 * HD;
            const short* kgB = kgb + (size_t)(kt + 3) * 64 * HD;
            const short* vgA = vgb + (kt + 2) * 64;
            const short* vgB = vgb + (kt + 3) * 64;
            kaA = *(const uint4*)(kgA + (size_t)t * 8);
            kcA = *(const uint4*)(kgA + (size_t)(t + 256) * 8);
            vaA = *(const uint4*)(vgA + (size_t)r0 * SEQ + bl0 * 8);
            vbA = *(const uint4*)(vgA + (size_t)r1 * SEQ + bl0 * 8);
            kaB = *(const uint4*)(kgB + (size_t)t * 8);
            kcB = *(const uint4*)(kgB + (size_t)(t + 256) * 8);
            vaB = *(const uint4*)(vgB + (size_t)r0 * SEQ + bl0 * 8);
            vbB = *(const uint4*)(vgB + (size_t)r1 * SEQ + bl0 * 8);
        }
        pv_tile(&Ks[kt & 3][0], &Vs[kt & 3][0], kt * 64);
        pv_tile(&Ks[(kt + 1) & 3][0], &Vs[(kt + 1) & 3][0], (kt + 1) * 64);
        if (kt < 30) {
            *(uint4*)(&Ks[(kt + 2) & 3][ds0]) = kaA;
            *(uint4*)(&Ks[(kt + 2) & 3][ds1]) = kcA;
            *(uint4*)(&Vs[(kt + 2) & 3][ds0]) = vaA;
            *(uint4*)(&Vs[(kt + 2) & 3][ds1]) = vbA;
            *(uint4*)(&Ks[(kt + 3) & 3][ds0]) = kaB;
            *(uint4*)(&Ks[(kt + 3) & 3][ds1]) = kcB;
            *(uint4*)(&Vs[(kt + 3) & 3][ds0]) = vaB;
            *(uint4*)(&Vs[(kt + 3) & 3][ds1]) = vbB;
        }
        __syncthreads();
    }

    // O epilogue: row = 4g+r, col = 16*sub + c ; one uint (hi<<16|lo) per elem
    const size_t abase = ((size_t)bh * SEQ + q0 + 16 * w) * HD;
#pragma unroll
    for (int r = 0; r < 4; ++r) {
        const size_t ro = abase + (size_t)(4 * g + r) * HD + c;
#pragma unroll
        for (int sub = 0; sub < 4; ++sub) {
            const float ov = (sub == 0) ? o0[r] : (sub == 1) ? o1[r]
                           : (sub == 2) ? o2[r] : o3[r];
            const unsigned short h16 = f2bf(ov);
            const unsigned short l16 = f2bf(ov - bf2f(h16));
            attn[ro + 16 * sub] = ((unsigned)h16 << 16) | l16;
        }
    }
}

// ---------------------------------------------------------------------------
// K3: out = concat(attn) @ Wo + bo on MFMA (3-term split-bf16).
// A loaded as packed uint (hi<<16|lo), unpacked to two bf16x8 frags.
// ---------------------------------------------------------------------------
__global__ __launch_bounds__(256) void mha_oproj_mfma(
    const unsigned* __restrict__ attn, const unsigned short* __restrict__ wto,
    const float* __restrict__ bo, float* __restrict__ out)
{
    const int m0 = blockIdx.x * 32;
    const int n0 = blockIdx.y * 64;
    const int t = threadIdx.x;
    const int w = t >> 6;
    const int lane = t & 63;
    const int g = lane >> 4;
    const int c = lane & 15;
    const int wm = w & 1, wn = w >> 1;

    const int mrow = m0 + 16 * wm + c;
    const int b_ = mrow >> 11, sm = mrow & 2047;
    const unsigned* ab = attn + ((size_t)(b_ * NHEADS) * SEQ + sm) * HD + 8 * g;
    const short* wh = (const short*)wto + 8 * g;
    const short* wl = wh + (size_t)EMBED * EMBED;

    f32x4 acc[2];
    acc[0] = (f32x4){0.f, 0.f, 0.f, 0.f};
    acc[1] = (f32x4){0.f, 0.f, 0.f, 0.f};

#pragma unroll 4
    for (int ch = 0; ch < 16; ++ch) {
        const size_t aoff = (size_t)(ch >> 1) * SEQ * HD + (ch & 1) * 32;
        const uint4 ua = *(const uint4*)(ab + aoff);
        const uint4 ub = *(const uint4*)(ab + aoff + 4);
        union { bf16x8 v; unsigned short s[8]; } a_h, a_l;
        a_h.s[0] = (unsigned short)(ua.x >> 16); a_l.s[0] = (unsigned short)(ua.x & 0xffffu);
        a_h.s[1] = (unsigned short)(ua.y >> 16); a_l.s[1] = (unsigned short)(ua.y & 0xffffu);
        a_h.s[2] = (unsigned short)(ua.z >> 16); a_l.s[2] = (unsigned short)(ua.z & 0xffffu);
        a_h.s[3] = (unsigned short)(ua.w >> 16); a_l.s[3] = (unsigned short)(ua.w & 0xffffu);
        a_h.s[4] = (unsigned short)(ub.x >> 16); a_l.s[4] = (unsigned short)(ub.x & 0xffffu);
        a_h.s[5] = (unsigned short)(ub.y >> 16); a_l.s[5] = (unsigned short)(ub.y & 0xffffu);
        a_h.s[6] = (unsigned short)(ub.z >> 16); a_l.s[6] = (unsigned short)(ub.z & 0xffffu);
        a_h.s[7] = (unsigned short)(ub.w >> 16); a_l.s[7] = (unsigned short)(ub.w & 0xffffu);
#pragma unroll
        for (int s = 0; s < 2; ++s) {
            const int n = n0 + 32 * wn + 16 * s + c;
            const size_t woff = (size_t)n * EMBED + 32 * ch;
            const bf16x8 b_h = *(const bf16x8*)(wh + woff);
            const bf16x8 b_l = *(const bf16x8*)(wl + woff);
            acc[s] = __builtin_amdgcn_mfma_f32_16x16x32_bf16(a_h.v, b_h, acc[s], 0, 0, 0);
            acc[s] = __builtin_amdgcn_mfma_f32_16x16x32_bf16(a_l.v, b_h, acc[s], 0, 0, 0);
            acc[s] = __builtin_amdgcn_mfma_f32_16x16x32_bf16(a_h.v, b_l, acc[s], 0, 0, 0);
        }
    }

#pragma unroll
    for (int s = 0; s < 2; ++s) {
        const int n = n0 + 32 * wn + 16 * s + c;
        const float bb = bo[n];
#pragma unroll
        for (int r = 0; r < 4; ++r) {
            const int m = m0 + 16 * wm + 4 * g + r;
            out[(size_t)m * EMBED + n] = acc[s][r] + bb;
        }
    }
}

// ---------------------------------------------------------------------------
extern "C" void kernel_launch(void* const* d_in, const int* in_sizes, int n_in,
                              void* d_out, int out_size, void* d_ws, size_t ws_size,
                              hipStream_t stream)
{
    const float* x  = (const float*)d_in[0];
    const float* Wq = (const float*)d_in[1];
    const float* bq = (const float*)d_in[2];
    const float* Wk = (const float*)d_in[3];
    const float* bk = (const float*)d_in[4];
    const float* Wv = (const float*)d_in[5];
    const float* bv = (const float*)d_in[6];
    const float* Wo = (const float*)d_in[7];
    const float* bo = (const float*)d_in[8];

    float* out = (float*)d_out;                      // [2,2048,512]
    float* wts = out + (size_t)2 * SEQ * EMBED;      // [2,8,2048,2048]

    unsigned short* qbw = (unsigned short*)d_ws;             // bf16 [16][2048][64]
    unsigned short* kbw = qbw + (size_t)NBH * SEQ * HD;      // bf16 [16][2048][64]
    unsigned short* vtw = kbw + (size_t)NBH * SEQ * HD;      // bf16 [16][64][2048] (kv-permuted)
    unsigned* attn = (unsigned*)(vtw + (size_t)NBH * SEQ * HD);  // uint [16][2048][64]
    unsigned short* xh  = (unsigned short*)(attn + (size_t)NBH * SEQ * HD);
    unsigned short* xl  = xh + (size_t)MROWS * EMBED;        // bf16 [4096][512]
    unsigned short* wtw = xl + (size_t)MROWS * EMBED;        // bf16 [3][512][512]
    unsigned short* wto = wtw + (size_t)3 * EMBED * EMBED;   // bf16 [2][512][512]

    cvt_x<<<dim3(MROWS * EMBED / 4 / 256), 256, 0, stream>>>(x, xh, xl);
    cvt_w<<<dim3(8, 8, 5), 256, 0, stream>>>(Wq, Wk, Wv, Wo, wtw, wto);
    mha_qkv_mfma<<<dim3(64, 24), 256, 0, stream>>>(xh, xl, wtw, bq, bk, bv,
                                                   qbw, kbw, vtw);
    mha_fused  <<<dim3(32, NBH), 256, 0, stream>>>((const short*)qbw, (const short*)kbw,
                                                   (const short*)vtw, wts, attn);
    mha_oproj_mfma<<<dim3(128, 8), 256, 0, stream>>>(attn, wto, bo, out);
}

// Round 11
// 193.440 us; speedup vs baseline: 1.0364x; 1.0364x over previous
//
#include <hip/hip_runtime.h>
#include <cstddef>

#define EMBED 512
#define NHEADS 8
#define HD 64
#define SEQ 2048
#define NBH 16      // B * NHEADS
#define MROWS 4096  // B * SEQ

typedef __attribute__((ext_vector_type(8))) short bf16x8;
typedef __attribute__((ext_vector_type(4))) float f32x4;

__device__ __forceinline__ unsigned short f2bf(float x) {
    union { float f; unsigned u; } v; v.f = x;
    unsigned r = v.u + 0x7fffu + ((v.u >> 16) & 1u);
    return (unsigned short)(r >> 16);
}
__device__ __forceinline__ float bf2f(unsigned short u) {
    union { unsigned u; float f; } v; v.u = ((unsigned)u) << 16;
    return v.f;
}

// ---------------------------------------------------------------------------
// K0a: split x (fp32) into x_hi + x_lo (bf16 each).
// ---------------------------------------------------------------------------
__global__ __launch_bounds__(256) void cvt_x(
    const float* __restrict__ x, unsigned short* __restrict__ xh,
    unsigned short* __restrict__ xl)
{
    const int i = blockIdx.x * 256 + threadIdx.x;      // float4 index
    float4 v = ((const float4*)x)[i];
    ushort4 h, lo;
    h.x = f2bf(v.x); lo.x = f2bf(v.x - bf2f(h.x));
    h.y = f2bf(v.y); lo.y = f2bf(v.y - bf2f(h.y));
    h.z = f2bf(v.z); lo.z = f2bf(v.z - bf2f(h.z));
    h.w = f2bf(v.w); lo.w = f2bf(v.w - bf2f(h.w));
    ((ushort4*)xh)[i] = h;
    ((ushort4*)xl)[i] = lo;
}

// ---------------------------------------------------------------------------
// K0b: weight transposes to bf16.  z=0..2: Wq/Wk/Wv -> wt[z][n][k] (hi only).
// z=3: Wo hi -> wto[0];  z=4: Wo lo -> wto[1].
// ---------------------------------------------------------------------------
__global__ __launch_bounds__(256) void cvt_w(
    const float* __restrict__ Wq, const float* __restrict__ Wk,
    const float* __restrict__ Wv, const float* __restrict__ Wo,
    unsigned short* __restrict__ wt, unsigned short* __restrict__ wto)
{
    __shared__ float Ws[64][65];
    const int z = blockIdx.z;
    const float* __restrict__ W = (z == 0) ? Wq : (z == 1) ? Wk : (z == 2) ? Wv : Wo;
    const int k0 = blockIdx.x * 64, n0 = blockIdx.y * 64;
    const int t = threadIdx.x;
#pragma unroll
    for (int l = 0; l < 4; ++l) {
        const int idx = t + 256 * l;
        const int r = idx >> 4, c4 = (idx & 15) * 4;
        float4 w = *(const float4*)(W + (size_t)(k0 + r) * EMBED + n0 + c4);
        Ws[r][c4 + 0] = w.x; Ws[r][c4 + 1] = w.y;
        Ws[r][c4 + 2] = w.z; Ws[r][c4 + 3] = w.w;
    }
    __syncthreads();
    unsigned short* __restrict__ dst =
        (z < 3) ? (wt + (size_t)z * EMBED * EMBED)
                : (wto + (size_t)(z - 3) * EMBED * EMBED);
#pragma unroll
    for (int l = 0; l < 4; ++l) {
        const int idx = t + 256 * l;
        const int rn = idx >> 4, k4 = (idx & 15) * 4;
        ushort4 o;
        if (z == 4) {
            float v0 = Ws[k4 + 0][rn], v1 = Ws[k4 + 1][rn];
            float v2 = Ws[k4 + 2][rn], v3 = Ws[k4 + 3][rn];
            o.x = f2bf(v0 - bf2f(f2bf(v0)));
            o.y = f2bf(v1 - bf2f(f2bf(v1)));
            o.z = f2bf(v2 - bf2f(f2bf(v2)));
            o.w = f2bf(v3 - bf2f(f2bf(v3)));
        } else {
            o.x = f2bf(Ws[k4 + 0][rn]);
            o.y = f2bf(Ws[k4 + 1][rn]);
            o.z = f2bf(Ws[k4 + 2][rn]);
            o.w = f2bf(Ws[k4 + 3][rn]);
        }
        *(ushort4*)(dst + (size_t)(n0 + rn) * EMBED + k0 + k4) = o;
    }
}

// ---------------------------------------------------------------------------
// K1: QKV projection on MFMA.  out = (x_hi + x_lo) @ W_z + b_z, bf16 out.
// v written to vt with per-32 kv permutation (so PV B-frags are 16B).
// ---------------------------------------------------------------------------
__global__ __launch_bounds__(256) void mha_qkv_mfma(
    const unsigned short* __restrict__ xh, const unsigned short* __restrict__ xl,
    const unsigned short* __restrict__ wt,
    const float* __restrict__ bq, const float* __restrict__ bk,
    const float* __restrict__ bv,
    unsigned short* __restrict__ qo, unsigned short* __restrict__ ko,
    unsigned short* __restrict__ vt)
{
    const int m0 = blockIdx.x * 64;
    const int z  = blockIdx.y >> 3;
    const int n0 = (blockIdx.y & 7) * 64;
    const float* __restrict__ bias = (z == 0) ? bq : (z == 1) ? bk : bv;

    const int t = threadIdx.x;
    const int w = t >> 6;
    const int lane = t & 63;
    const int g = lane >> 4;
    const int c = lane & 15;

    const short* ah_row = (const short*)xh + (size_t)(m0 + 16 * w + c) * EMBED + 8 * g;
    const short* al_row = (const short*)xl + (size_t)(m0 + 16 * w + c) * EMBED + 8 * g;
    const short* wz = (const short*)wt + (size_t)z * EMBED * EMBED + 8 * g;

    f32x4 acc[4];
#pragma unroll
    for (int s = 0; s < 4; ++s) acc[s] = (f32x4){0.f, 0.f, 0.f, 0.f};

#pragma unroll 4
    for (int ch = 0; ch < 16; ++ch) {
        const int k0 = ch * 32;
        const bf16x8 ah = *(const bf16x8*)(ah_row + k0);
        const bf16x8 al = *(const bf16x8*)(al_row + k0);
#pragma unroll
        for (int s = 0; s < 4; ++s) {
            const bf16x8 bs = *(const bf16x8*)(wz + (size_t)(n0 + 16 * s + c) * EMBED + k0);
            acc[s] = __builtin_amdgcn_mfma_f32_16x16x32_bf16(ah, bs, acc[s], 0, 0, 0);
            acc[s] = __builtin_amdgcn_mfma_f32_16x16x32_bf16(al, bs, acc[s], 0, 0, 0);
        }
    }

    if (z < 2) {
        unsigned short* __restrict__ out = (z == 0) ? qo : ko;
#pragma unroll
        for (int s = 0; s < 4; ++s) {
            const int n = n0 + 16 * s + c;
            const int h = n >> 6, d = n & 63;
            const float bb = bias[n];
#pragma unroll
            for (int r = 0; r < 4; ++r) {
                const int m  = m0 + 16 * w + 4 * g + r;
                const int b_ = m >> 11, sm = m & 2047;
                out[((size_t)(b_ * NHEADS + h) * SEQ + sm) * HD + d] =
                    f2bf(acc[s][r] + bb);
            }
        }
    } else {
        const int m  = m0 + 16 * w + 4 * g;     // base kv of the 4-row chunk
        const int b_ = m >> 11, sm = m & 2047;
        const int a  = sm >> 5, rem = sm & 31;
        const int pos = 32 * a + 8 * ((rem & 15) >> 2) + ((rem >> 4) << 2);
        const int h  = n0 >> 6;
#pragma unroll
        for (int s = 0; s < 4; ++s) {
            const int d = 16 * s + c;
            const float bb = bias[n0 + d];
            ushort4 o;
            o.x = f2bf(acc[s][0] + bb);
            o.y = f2bf(acc[s][1] + bb);
            o.z = f2bf(acc[s][2] + bb);
            o.w = f2bf(acc[s][3] + bb);
            *(ushort4*)(vt + ((size_t)(b_ * NHEADS + h) * HD + d) * SEQ + pos) = o;
        }
    }
}

// ---------------------------------------------------------------------------
// K2: fused flash attention, SPLIT-KV: 8 waves/block (512 thr), group A
// (w<4) handles kv [0,1024), group B (w>=4) kv [1024,2048) for the same 64
// q rows.  l merged via LDS between passes; partial O merged via LDS at the
// end.  16 waves/CU = 4 waves/SIMD (was 2).  K/V LDS-staged, XOR-swizzled,
// double-buffered per group.  P packed to bf16 by truncation.
// ---------------------------------------------------------------------------
__global__ __launch_bounds__(512, 4) void mha_fused(
    const short* __restrict__ qb, const short* __restrict__ kb,
    const short* __restrict__ vt,
    float* __restrict__ wts, unsigned* __restrict__ attn)
{
    __shared__ short KsA[2][4096];
    __shared__ short VsA[2][4096];
    __shared__ short KsB[2][4096];
    __shared__ short VsB[2][4096];
    __shared__ float lx[512];

    const int bh = blockIdx.y;
    const int q0 = blockIdx.x * 64;
    const int t = threadIdx.x;
    const int w = t >> 6;          // 0..7
    const int grp = w >> 2;        // 0: kv [0,1024)  1: kv [1024,2048)
    const int wq = w & 3;          // q sub-tile
    const int lane = t & 63;
    const int g = lane >> 4;
    const int c = lane & 15;
    const int q = q0 + wq * 16 + c;

    const short* qrow = qb + ((size_t)bh * SEQ + q) * HD + 8 * g;
    const bf16x8 qf0 = *(const bf16x8*)(qrow);
    const bf16x8 qf1 = *(const bf16x8*)(qrow + 32);

    // staging: one 16B chunk per thread per 8KB tile
    const int rs = t >> 3, bls = t & 7;
    const int dss = rs * 64 + ((bls ^ (rs & 7)) << 3);
    const short* kgb = kb + (size_t)bh * SEQ * HD;
    const short* vgb = vt + (size_t)bh * HD * SEQ;

    int koff[4][2];
#pragma unroll
    for (int s = 0; s < 4; ++s) {
        const int rr = c + 16 * s;
        koff[s][0] = rr * 64 + (((g    ) ^ (rr & 7)) << 3);
        koff[s][1] = rr * 64 + (((g + 4) ^ (rr & 7)) << 3);
    }
    int voff2[4][2];
#pragma unroll
    for (int s = 0; s < 4; ++s) {
        const int rv = 16 * s + c;
        voff2[s][0] = rv * 64 + (((g    ) ^ (rv & 7)) << 3);
        voff2[s][1] = rv * 64 + (((g + 4) ^ (rv & 7)) << 3);
    }

    const float scale2 = 0.125f * 1.44269504f;   // 1/sqrt(64) * log2(e)
    const int ktg0 = grp * 16;                   // group's first global k-tile

    // ---- pass 1: row sums of exp2(s*scale2), each group over its half ---
    float l = 0.f;

    auto sum_tile = [&](const short* Kb) {
        f32x4 a0 = {0.f,0.f,0.f,0.f}, a1 = {0.f,0.f,0.f,0.f};
        f32x4 a2 = {0.f,0.f,0.f,0.f}, a3 = {0.f,0.f,0.f,0.f};
        __builtin_amdgcn_s_setprio(1);
        a0 = __builtin_amdgcn_mfma_f32_16x16x32_bf16(*(const bf16x8*)(Kb + koff[0][0]), qf0, a0, 0, 0, 0);
        a0 = __builtin_amdgcn_mfma_f32_16x16x32_bf16(*(const bf16x8*)(Kb + koff[0][1]), qf1, a0, 0, 0, 0);
        a1 = __builtin_amdgcn_mfma_f32_16x16x32_bf16(*(const bf16x8*)(Kb + koff[1][0]), qf0, a1, 0, 0, 0);
        a1 = __builtin_amdgcn_mfma_f32_16x16x32_bf16(*(const bf16x8*)(Kb + koff[1][1]), qf1, a1, 0, 0, 0);
        a2 = __builtin_amdgcn_mfma_f32_16x16x32_bf16(*(const bf16x8*)(Kb + koff[2][0]), qf0, a2, 0, 0, 0);
        a2 = __builtin_amdgcn_mfma_f32_16x16x32_bf16(*(const bf16x8*)(Kb + koff[2][1]), qf1, a2, 0, 0, 0);
        a3 = __builtin_amdgcn_mfma_f32_16x16x32_bf16(*(const bf16x8*)(Kb + koff[3][0]), qf0, a3, 0, 0, 0);
        a3 = __builtin_amdgcn_mfma_f32_16x16x32_bf16(*(const bf16x8*)(Kb + koff[3][1]), qf1, a3, 0, 0, 0);
        __builtin_amdgcn_s_setprio(0);
        float ts = 0.f;
#pragma unroll
        for (int r = 0; r < 4; ++r) {
            ts += __builtin_amdgcn_exp2f(a0[r] * scale2);
            ts += __builtin_amdgcn_exp2f(a1[r] * scale2);
            ts += __builtin_amdgcn_exp2f(a2[r] * scale2);
            ts += __builtin_amdgcn_exp2f(a3[r] * scale2);
        }
        ts += __shfl_xor(ts, 16);
        ts += __shfl_xor(ts, 32);
        l += ts;
    };

    {   // prologue: stage local tile 0 of both groups
        uint4 kA = *(const uint4*)(kgb + (size_t)0  * 64 * HD + (size_t)t * 8);
        uint4 kB = *(const uint4*)(kgb + (size_t)16 * 64 * HD + (size_t)t * 8);
        *(uint4*)(&KsA[0][dss]) = kA;
        *(uint4*)(&KsB[0][dss]) = kB;
    }
    __syncthreads();
    int cur = 0;
    for (int ktl = 0; ktl < 16; ++ktl) {
        uint4 nA, nB;
        if (ktl < 15) {
            nA = *(const uint4*)(kgb + (size_t)(ktl + 1)  * 64 * HD + (size_t)t * 8);
            nB = *(const uint4*)(kgb + (size_t)(ktl + 17) * 64 * HD + (size_t)t * 8);
        }
        sum_tile(grp ? &KsB[cur][0] : &KsA[cur][0]);
        if (ktl < 15) {
            *(uint4*)(&KsA[cur ^ 1][dss]) = nA;
            *(uint4*)(&KsB[cur ^ 1][dss]) = nB;
        }
        __syncthreads();
        cur ^= 1;
    }

    // merge l across partner waves (w ^ 4  <=>  t ^ 256)
    lx[t] = l;
    __syncthreads();
    l = lx[t] + lx[t ^ 256];
    const float c0 = -__builtin_amdgcn_logf(l);   // p = exp2(s*scale2 + c0)
    __syncthreads();

    // ---- pass 2: weights + PV over this group's half --------------------
    f32x4 o0 = {0.f,0.f,0.f,0.f}, o1 = {0.f,0.f,0.f,0.f};
    f32x4 o2 = {0.f,0.f,0.f,0.f}, o3 = {0.f,0.f,0.f,0.f};
    float* __restrict__ wrow = wts + ((size_t)bh * SEQ + q) * SEQ;

    auto pv_tile = [&](const short* Kb, const short* Vb, int kv0) {
        f32x4 a0 = {0.f,0.f,0.f,0.f}, a1 = {0.f,0.f,0.f,0.f};
        f32x4 a2 = {0.f,0.f,0.f,0.f}, a3 = {0.f,0.f,0.f,0.f};
        __builtin_amdgcn_s_setprio(1);
        a0 = __builtin_amdgcn_mfma_f32_16x16x32_bf16(*(const bf16x8*)(Kb + koff[0][0]), qf0, a0, 0, 0, 0);
        a0 = __builtin_amdgcn_mfma_f32_16x16x32_bf16(*(const bf16x8*)(Kb + koff[0][1]), qf1, a0, 0, 0, 0);
        a1 = __builtin_amdgcn_mfma_f32_16x16x32_bf16(*(const bf16x8*)(Kb + koff[1][0]), qf0, a1, 0, 0, 0);
        a1 = __builtin_amdgcn_mfma_f32_16x16x32_bf16(*(const bf16x8*)(Kb + koff[1][1]), qf1, a1, 0, 0, 0);
        a2 = __builtin_amdgcn_mfma_f32_16x16x32_bf16(*(const bf16x8*)(Kb + koff[2][0]), qf0, a2, 0, 0, 0);
        a2 = __builtin_amdgcn_mfma_f32_16x16x32_bf16(*(const bf16x8*)(Kb + koff[2][1]), qf1, a2, 0, 0, 0);
        a3 = __builtin_amdgcn_mfma_f32_16x16x32_bf16(*(const bf16x8*)(Kb + koff[3][0]), qf0, a3, 0, 0, 0);
        a3 = __builtin_amdgcn_mfma_f32_16x16x32_bf16(*(const bf16x8*)(Kb + koff[3][1]), qf1, a3, 0, 0, 0);
        __builtin_amdgcn_s_setprio(0);

        float pn[4][4];
#pragma unroll
        for (int r = 0; r < 4; ++r) {
            pn[0][r] = __builtin_amdgcn_exp2f(fmaf(a0[r], scale2, c0));
            pn[1][r] = __builtin_amdgcn_exp2f(fmaf(a1[r], scale2, c0));
            pn[2][r] = __builtin_amdgcn_exp2f(fmaf(a2[r], scale2, c0));
            pn[3][r] = __builtin_amdgcn_exp2f(fmaf(a3[r], scale2, c0));
        }
        // P pack by truncation (p >= 0; bias <= 2^-9 relative)
        union { bf16x8 v; unsigned u[4]; } pf0, pf1;
        pf0.u[0] = (__float_as_uint(pn[0][0]) >> 16) | (__float_as_uint(pn[0][1]) & 0xffff0000u);
        pf0.u[1] = (__float_as_uint(pn[0][2]) >> 16) | (__float_as_uint(pn[0][3]) & 0xffff0000u);
        pf0.u[2] = (__float_as_uint(pn[1][0]) >> 16) | (__float_as_uint(pn[1][1]) & 0xffff0000u);
        pf0.u[3] = (__float_as_uint(pn[1][2]) >> 16) | (__float_as_uint(pn[1][3]) & 0xffff0000u);
        pf1.u[0] = (__float_as_uint(pn[2][0]) >> 16) | (__float_as_uint(pn[2][1]) & 0xffff0000u);
        pf1.u[1] = (__float_as_uint(pn[2][2]) >> 16) | (__float_as_uint(pn[2][3]) & 0xffff0000u);
        pf1.u[2] = (__float_as_uint(pn[3][0]) >> 16) | (__float_as_uint(pn[3][1]) & 0xffff0000u);
        pf1.u[3] = (__float_as_uint(pn[3][2]) >> 16) | (__float_as_uint(pn[3][3]) & 0xffff0000u);

        __builtin_amdgcn_s_setprio(1);
#pragma unroll
        for (int sub = 0; sub < 4; ++sub) {
            const bf16x8 vf0 = *(const bf16x8*)(Vb + voff2[sub][0]);
            const bf16x8 vf1 = *(const bf16x8*)(Vb + voff2[sub][1]);
            f32x4& o = (sub == 0) ? o0 : (sub == 1) ? o1 : (sub == 2) ? o2 : o3;
            o = __builtin_amdgcn_mfma_f32_16x16x32_bf16(pf0.v, vf0, o, 0, 0, 0);
            o = __builtin_amdgcn_mfma_f32_16x16x32_bf16(pf1.v, vf1, o, 0, 0, 0);
        }
        __builtin_amdgcn_s_setprio(0);
#pragma unroll
        for (int s = 0; s < 4; ++s) {
            float4 st;
            st.x = pn[s][0]; st.y = pn[s][1]; st.z = pn[s][2]; st.w = pn[s][3];
            *(float4*)(wrow + kv0 + 16 * s + 4 * g) = st;
        }
    };

    {   // prologue: stage K and V local tile 0 of both groups
        uint4 kA = *(const uint4*)(kgb + (size_t)0  * 64 * HD + (size_t)t * 8);
        uint4 kB = *(const uint4*)(kgb + (size_t)16 * 64 * HD + (size_t)t * 8);
        uint4 vA = *(const uint4*)(vgb + (size_t)rs * SEQ + 0    + bls * 8);
        uint4 vB = *(const uint4*)(vgb + (size_t)rs * SEQ + 1024 + bls * 8);
        *(uint4*)(&KsA[0][dss]) = kA;  *(uint4*)(&KsB[0][dss]) = kB;
        *(uint4*)(&VsA[0][dss]) = vA;  *(uint4*)(&VsB[0][dss]) = vB;
    }
    __syncthreads();
    cur = 0;
    for (int ktl = 0; ktl < 16; ++ktl) {
        uint4 nKA, nKB, nVA, nVB;
        if (ktl < 15) {
            nKA = *(const uint4*)(kgb + (size_t)(ktl + 1)  * 64 * HD + (size_t)t * 8);
            nKB = *(const uint4*)(kgb + (size_t)(ktl + 17) * 64 * HD + (size_t)t * 8);
            nVA = *(const uint4*)(vgb + (size_t)rs * SEQ + (ktl + 1)  * 64 + bls * 8);
            nVB = *(const uint4*)(vgb + (size_t)rs * SEQ + (ktl + 17) * 64 + bls * 8);
        }
        if (grp == 0) pv_tile(&KsA[cur][0], &VsA[cur][0], ktl * 64);
        else          pv_tile(&KsB[cur][0], &VsB[cur][0], 1024 + ktl * 64);
        if (ktl < 15) {
            *(uint4*)(&KsA[cur ^ 1][dss]) = nKA;  *(uint4*)(&KsB[cur ^ 1][dss]) = nKB;
            *(uint4*)(&VsA[cur ^ 1][dss]) = nVA;  *(uint4*)(&VsB[cur ^ 1][dss]) = nVB;
        }
        __syncthreads();
        cur ^= 1;
    }

    // ---- merge partial O across groups, write packed attn ---------------
    float* sc = (float*)&KsA[0][0];   // 16 KB scratch (KsA region, done with)
    if (w >= 4) {
        const int base = ((w - 4) * 64 + lane) * 16;
#pragma unroll
        for (int r = 0; r < 4; ++r) {
            sc[base + 0  + r] = o0[r];
            sc[base + 4  + r] = o1[r];
            sc[base + 8  + r] = o2[r];
            sc[base + 12 + r] = o3[r];
        }
    }
    __syncthreads();
    if (w < 4) {
        const int base = (w * 64 + lane) * 16;
        const size_t abase = ((size_t)bh * SEQ + q0 + 16 * w) * HD;
#pragma unroll
        for (int r = 0; r < 4; ++r) {
            const float v0 = o0[r] + sc[base + 0  + r];
            const float v1 = o1[r] + sc[base + 4  + r];
            const float v2 = o2[r] + sc[base + 8  + r];
            const float v3 = o3[r] + sc[base + 12 + r];
            const size_t ro = abase + (size_t)(4 * g + r) * HD + c;
            unsigned short h16, l16;
            h16 = f2bf(v0); l16 = f2bf(v0 - bf2f(h16));
            attn[ro +  0] = ((unsigned)h16 << 16) | l16;
            h16 = f2bf(v1); l16 = f2bf(v1 - bf2f(h16));
            attn[ro + 16] = ((unsigned)h16 << 16) | l16;
            h16 = f2bf(v2); l16 = f2bf(v2 - bf2f(h16));
            attn[ro + 32] = ((unsigned)h16 << 16) | l16;
            h16 = f2bf(v3); l16 = f2bf(v3 - bf2f(h16));
            attn[ro + 48] = ((unsigned)h16 << 16) | l16;
        }
    }
}

// ---------------------------------------------------------------------------
// K3: out = concat(attn) @ Wo + bo on MFMA (3-term split-bf16).
// A loaded as packed uint (hi<<16|lo), unpacked to two bf16x8 frags.
// ---------------------------------------------------------------------------
__global__ __launch_bounds__(256) void mha_oproj_mfma(
    const unsigned* __restrict__ attn, const unsigned short* __restrict__ wto,
    const float* __restrict__ bo, float* __restrict__ out)
{
    const int m0 = blockIdx.x * 32;
    const int n0 = blockIdx.y * 64;
    const int t = threadIdx.x;
    const int w = t >> 6;
    const int lane = t & 63;
    const int g = lane >> 4;
    const int c = lane & 15;
    const int wm = w & 1, wn = w >> 1;

    const int mrow = m0 + 16 * wm + c;
    const int b_ = mrow >> 11, sm = mrow & 2047;
    const unsigned* ab = attn + ((size_t)(b_ * NHEADS) * SEQ + sm) * HD + 8 * g;
    const short* wh = (const short*)wto + 8 * g;
    const short* wl = wh + (size_t)EMBED * EMBED;

    f32x4 acc[2];
    acc[0] = (f32x4){0.f, 0.f, 0.f, 0.f};
    acc[1] = (f32x4){0.f, 0.f, 0.f, 0.f};

#pragma unroll 4
    for (int ch = 0; ch < 16; ++ch) {
        const size_t aoff = (size_t)(ch >> 1) * SEQ * HD + (ch & 1) * 32;
        const uint4 ua = *(const uint4*)(ab + aoff);
        const uint4 ub = *(const uint4*)(ab + aoff + 4);
        union { bf16x8 v; unsigned short s[8]; } a_h, a_l;
        a_h.s[0] = (unsigned short)(ua.x >> 16); a_l.s[0] = (unsigned short)(ua.x & 0xffffu);
        a_h.s[1] = (unsigned short)(ua.y >> 16); a_l.s[1] = (unsigned short)(ua.y & 0xffffu);
        a_h.s[2] = (unsigned short)(ua.z >> 16); a_l.s[2] = (unsigned short)(ua.z & 0xffffu);
        a_h.s[3] = (unsigned short)(ua.w >> 16); a_l.s[3] = (unsigned short)(ua.w & 0xffffu);
        a_h.s[4] = (unsigned short)(ub.x >> 16); a_l.s[4] = (unsigned short)(ub.x & 0xffffu);
        a_h.s[5] = (unsigned short)(ub.y >> 16); a_l.s[5] = (unsigned short)(ub.y & 0xffffu);
        a_h.s[6] = (unsigned short)(ub.z >> 16); a_l.s[6] = (unsigned short)(ub.z & 0xffffu);
        a_h.s[7] = (unsigned short)(ub.w >> 16); a_l.s[7] = (unsigned short)(ub.w & 0xffffu);
#pragma unroll
        for (int s = 0; s < 2; ++s) {
            const int n = n0 + 32 * wn + 16 * s + c;
            const size_t woff = (size_t)n * EMBED + 32 * ch;
            const bf16x8 b_h = *(const bf16x8*)(wh + woff);
            const bf16x8 b_l = *(const bf16x8*)(wl + woff);
            acc[s] = __builtin_amdgcn_mfma_f32_16x16x32_bf16(a_h.v, b_h, acc[s], 0, 0, 0);
            acc[s] = __builtin_amdgcn_mfma_f32_16x16x32_bf16(a_l.v, b_h, acc[s], 0, 0, 0);
            acc[s] = __builtin_amdgcn_mfma_f32_16x16x32_bf16(a_h.v, b_l, acc[s], 0, 0, 0);
        }
    }

#pragma unroll
    for (int s = 0; s < 2; ++s) {
        const int n = n0 + 32 * wn + 16 * s + c;
        const float bb = bo[n];
#pragma unroll
        for (int r = 0; r < 4; ++r) {
            const int m = m0 + 16 * wm + 4 * g + r;
            out[(size_t)m * EMBED + n] = acc[s][r] + bb;
        }
    }
}

// ---------------------------------------------------------------------------
extern "C" void kernel_launch(void* const* d_in, const int* in_sizes, int n_in,
                              void* d_out, int out_size, void* d_ws, size_t ws_size,
                              hipStream_t stream)
{
    const float* x  = (const float*)d_in[0];
    const float* Wq = (const float*)d_in[1];
    const float* bq = (const float*)d_in[2];
    const float* Wk = (const float*)d_in[3];
    const float* bk = (const float*)d_in[4];
    const float* Wv = (const float*)d_in[5];
    const float* bv = (const float*)d_in[6];
    const float* Wo = (const float*)d_in[7];
    const float* bo = (const float*)d_in[8];

    float* out = (float*)d_out;                      // [2,2048,512]
    float* wts = out + (size_t)2 * SEQ * EMBED;      // [2,8,2048,2048]

    unsigned short* qbw = (unsigned short*)d_ws;             // bf16 [16][2048][64]
    unsigned short* kbw = qbw + (size_t)NBH * SEQ * HD;      // bf16 [16][2048][64]
    unsigned short* vtw = kbw + (size_t)NBH * SEQ * HD;      // bf16 [16][64][2048] (kv-permuted)
    unsigned* attn = (unsigned*)(vtw + (size_t)NBH * SEQ * HD);  // uint [16][2048][64]
    unsigned short* xh  = (unsigned short*)(attn + (size_t)NBH * SEQ * HD);
    unsigned short* xl  = xh + (size_t)MROWS * EMBED;        // bf16 [4096][512]
    unsigned short* wtw = xl + (size_t)MROWS * EMBED;        // bf16 [3][512][512]
    unsigned short* wto = wtw + (size_t)3 * EMBED * EMBED;   // bf16 [2][512][512]

    cvt_x<<<dim3(MROWS * EMBED / 4 / 256), 256, 0, stream>>>(x, xh, xl);
    cvt_w<<<dim3(8, 8, 5), 256, 0, stream>>>(Wq, Wk, Wv, Wo, wtw, wto);
    mha_qkv_mfma<<<dim3(64, 24), 256, 0, stream>>>(xh, xl, wtw, bq, bk, bv,
                                                   qbw, kbw, vtw);
    mha_fused  <<<dim3(32, NBH), 512, 0, stream>>>((const short*)qbw, (const short*)kbw,
                                                   (const short*)vtw, wts, attn);
    mha_oproj_mfma<<<dim3(128, 8), 256, 0, stream>>>(attn, wto, bo, out);
}